// Round 6
// baseline (568.977 us; speedup 1.0000x reference)
//
#include <hip/hip_runtime.h>
#include <hip/hip_bf16.h>

// S = (Q K^T)/32 * mask (multiplicative), attn = softmax(S), ctx = attn * K.
// d_out = ctx (8*2048*1024 f32) ++ attn (8*2048*2048 f32).
// R8 = R7 with the vmcnt accounting FIXED (R7 counted 2 instr/step, actual is
// 4 instr/step/wave -> its waits were no-ops and steps were read before landing).
// Structure: 4-wave 128x128 BK=32 blocks, 4 rotating LDS regions (64 KiB/block ->
// 2 blocks/CU for cross-block stall overlap), 3-step lookahead, counted vmcnt(8).

typedef __attribute__((ext_vector_type(8))) short bf16x8;
typedef __attribute__((ext_vector_type(4))) float f32x4;
typedef __attribute__((ext_vector_type(4))) unsigned u32x4;
typedef __attribute__((ext_vector_type(2))) unsigned u32x2;

constexpr int BATCH = 8;
constexpr int LQ    = 2048;
constexpr int LKK   = 2048;
constexpr int DH    = 1024;
constexpr float SCALE = 0.03125f;   // 1/sqrt(1024)

#define GAS(p) ((const __attribute__((address_space(1))) void*)(p))
#define LAS(p) ((__attribute__((address_space(3))) void*)(p))

// 32-bit LDS byte offset of a generic pointer into __shared__
__device__ __forceinline__ unsigned lds_addr(const unsigned short* p) {
    return (unsigned)(unsigned long long)
        (const __attribute__((address_space(3))) unsigned short*)p;
}

// opaque LDS read (rule 18: caller waits lgkmcnt + sched_barrier(0) before use)
__device__ __forceinline__ bf16x8 dsr_b128(unsigned off) {
    bf16x8 r;
    asm volatile("ds_read_b128 %0, %1" : "=v"(r) : "v"(off));
    return r;
}

// round-half-up fp32->bf16 pair pack (2 adds + v_perm)
__device__ __forceinline__ unsigned pack_bf16x2(float x0, float x1) {
    unsigned a = __builtin_bit_cast(unsigned, x0) + 0x8000u;
    unsigned b = __builtin_bit_cast(unsigned, x1) + 0x8000u;
    return __builtin_amdgcn_perm(b, a, 0x07060302u);  // mem order: x0.hi16, x1.hi16
}

__device__ __forceinline__ unsigned short pack_bf16(float x) {
    return (unsigned short)((__builtin_bit_cast(unsigned, x) + 0x8000u) >> 16);
}

// ---------------- prep: Q (and K if fallback) fp32 -> bf16 ------------------------
__global__ __launch_bounds__(256)
void cvt_kernel(const float* __restrict__ Q, const float* __restrict__ K,
                unsigned short* __restrict__ Qb, unsigned short* __restrict__ Kb) {
    const int bid = blockIdx.x;
    const float* src; unsigned short* dst; size_t off;
    if (bid < 4096) { src = Q; dst = Qb; off = (size_t)bid * 4096; }
    else            { src = K; dst = Kb; off = (size_t)(bid - 4096) * 4096; }
    off += (size_t)threadIdx.x * 16;
    const f32x4 a = *(const f32x4*)(src + off);
    const f32x4 b = *(const f32x4*)(src + off + 4);
    const f32x4 c = *(const f32x4*)(src + off + 8);
    const f32x4 d = *(const f32x4*)(src + off + 12);
    u32x4 v0, v1;
    v0[0] = pack_bf16x2(a[0], a[1]); v0[1] = pack_bf16x2(a[2], a[3]);
    v0[2] = pack_bf16x2(b[0], b[1]); v0[3] = pack_bf16x2(b[2], b[3]);
    v1[0] = pack_bf16x2(c[0], c[1]); v1[1] = pack_bf16x2(c[2], c[3]);
    v1[2] = pack_bf16x2(d[0], d[1]); v1[3] = pack_bf16x2(d[2], d[3]);
    *(u32x4*)(dst + off)     = v0;
    *(u32x4*)(dst + off + 8) = v1;
}

// ---------------- prep: K fp32 -> K^T bf16 (LDS transpose) AND row-major Kb -------
__global__ __launch_bounds__(256)
void kt_kernel(const float* __restrict__ K, unsigned short* __restrict__ KT,
               unsigned short* __restrict__ Kb) {
    __shared__ unsigned short T[64 * 68];
    const int b  = blockIdx.z;
    const int k0 = blockIdx.y * 64;
    const int d0 = blockIdx.x * 64;
    const int t  = threadIdx.x;
    const int k4 = (t >> 4) * 4;
    const int d4 = (t & 15) * 4;
    f32x4 rk[4];
    const float* Kp = K + ((size_t)b * LKK + k0 + k4) * DH + d0 + d4;
#pragma unroll
    for (int j = 0; j < 4; ++j) rk[j] = *(const f32x4*)(Kp + (size_t)j * DH);
    unsigned short* Kbp = Kb + ((size_t)b * LKK + k0 + k4) * DH + d0 + d4;
#pragma unroll
    for (int j = 0; j < 4; ++j) {
        u32x2 w;
        w[0] = pack_bf16x2(rk[j][0], rk[j][1]);
        w[1] = pack_bf16x2(rk[j][2], rk[j][3]);
        *(u32x2*)(Kbp + (size_t)j * DH) = w;
    }
#pragma unroll
    for (int c = 0; c < 4; ++c) {
        u32x2 w;
        w[0] = pack_bf16x2(rk[0][c], rk[1][c]);
        w[1] = pack_bf16x2(rk[2][c], rk[3][c]);
        *(u32x2*)&T[(d4 + c) * 68 + k4] = w;
    }
    __syncthreads();
    const int d  = t >> 2;
    const int kc = (t & 3) * 16;
    u32x2 a0 = *(const u32x2*)&T[d * 68 + kc];
    u32x2 a1 = *(const u32x2*)&T[d * 68 + kc + 4];
    u32x2 a2 = *(const u32x2*)&T[d * 68 + kc + 8];
    u32x2 a3 = *(const u32x2*)&T[d * 68 + kc + 12];
    unsigned short* dst = KT + ((size_t)b * DH + d0 + d) * LKK + k0 + kc;
    u32x4 w0; w0[0] = a0[0]; w0[1] = a0[1]; w0[2] = a1[0]; w0[3] = a1[1];
    u32x4 w1; w1[0] = a2[0]; w1[1] = a2[1]; w1[2] = a3[0]; w1[3] = a3[1];
    *(u32x4*)dst       = w0;
    *(u32x4*)(dst + 8) = w1;
}

// ================= 128x128 BK=32 4-region pipelined mainloop (R8) ==================
// 4 waves (2M x 2N), wave-tile 64x64, acc[4][4]. LDS: per matrix 4 regions x
// [128 rows][32 k bf16] = 32 KiB; total 64 KiB -> 2 blocks/CU.
// Per step, per wave: 4 global_load_lds instructions (2 row-halves x {A,B}).
// Region r = s&3. Live set at step s: read s&3, landed (s+1)&3, in-flight (s+2)&3,
// writing (s+3)&3 — all distinct.
// vmcnt accounting (4 instr/step/wave — R7's fatal bug was counting 2):
//   RAW: at step s end, issued = steps 0..s+3; vmcnt(8) leaves only steps
//        s+2,s+3 in flight -> step s+1 landed before its reads (all waves wait
//        before the end barrier, so cross-wave fills are also covered).
//   prologue: 12 issued, vmcnt(8) -> step 0 landed.
//   tail: s==NS-3 -> vmcnt(4) (step NS-2 landed); s==NS-2 -> vmcnt(0).
//   WAR: stage(s+3) (issued step s) targets region (s-1)&3, whose reads drained
//        at each wave's lgkmcnt(0) in step s-1, before that step's end barrier.
// Chunk swizzle: 16B chunk c of row r at slot c ^ ((r>>1)&3); write side realized
// by pre-swizzling the GLOBAL source column (gload_lds dest stays linear).
template<int LDA, int LDB, int NS>
__device__ __forceinline__ void gemm4_mainloop(
    const unsigned short* __restrict__ Ab,
    const unsigned short* __restrict__ Bb,
    unsigned short* lA, unsigned short* lB,
    f32x4 (&acc)[4][4])
{
    const int tid  = threadIdx.x;
    const int lane = tid & 63;
    const int wid  = tid >> 6;          // 0..3
    const int wm   = (wid & 1) * 64;
    const int wn   = (wid >> 1) * 64;
    const int lrow = lane & 15;
    const int quad = lane >> 4;
    const int slotsw = (quad ^ ((lrow >> 1) & 3)) * 8;      // swizzled read slot

    const int srow = wid * 16 + (lane >> 2);                // staging row (call c adds c*64)
    const int sc   = ((lane & 3) ^ ((lane >> 3) & 3)) * 8;  // pre-swizzled source col

    auto stage = [&](int step, int r2) {
#pragma unroll
        for (int c = 0; c < 2; ++c) {
            const int row = c * 64 + srow;
            unsigned short* dA = lA + r2 * 4096 + c * 2048 + wid * 512;
            unsigned short* dB = lB + r2 * 4096 + c * 2048 + wid * 512;
            __builtin_amdgcn_global_load_lds(GAS(Ab + (size_t)row * LDA + step * 32 + sc),
                                             LAS(dA), 16, 0, 0);
            __builtin_amdgcn_global_load_lds(GAS(Bb + (size_t)row * LDB + step * 32 + sc),
                                             LAS(dB), 16, 0, 0);
        }
    };

#pragma unroll
    for (int i = 0; i < 4; ++i)
#pragma unroll
        for (int j = 0; j < 4; ++j) acc[i][j] = (f32x4){0.f, 0.f, 0.f, 0.f};

    // prologue: steps 0..2 in flight (12 instr/wave); land step 0
    stage(0, 0); stage(1, 1); stage(2, 2);
    asm volatile("s_waitcnt vmcnt(8)" ::: "memory");
    __builtin_amdgcn_s_barrier();

    for (int s4 = 0; s4 < NS; s4 += 4) {
#pragma unroll
        for (int u = 0; u < 4; ++u) {
            const int s = s4 + u;
            const int r  = u;                // s&3 (s4 % 4 == 0)
            const int r2 = (u + 3) & 3;      // (s+3)&3
            bf16x8 af[4], bfr[4];
#pragma unroll
            for (int nf = 0; nf < 4; ++nf)
                bfr[nf] = dsr_b128(lds_addr(&lB[r * 4096 + (wn + nf * 16 + lrow) * 32 + slotsw]));
#pragma unroll
            for (int mf = 0; mf < 4; ++mf)
                af[mf] = dsr_b128(lds_addr(&lA[r * 4096 + (wm + mf * 16 + lrow) * 32 + slotsw]));

            if (s + 3 < NS) stage(s + 3, r2);

            __builtin_amdgcn_s_barrier();
            asm volatile("s_waitcnt lgkmcnt(0)" ::: "memory");
            __builtin_amdgcn_sched_barrier(0);
            __builtin_amdgcn_s_setprio(1);
#pragma unroll
            for (int mf = 0; mf < 4; ++mf)
#pragma unroll
                for (int nf = 0; nf < 4; ++nf)
                    acc[mf][nf] = __builtin_amdgcn_mfma_f32_16x16x32_bf16(
                        af[mf], bfr[nf], acc[mf][nf], 0, 0, 0);
            __builtin_amdgcn_s_setprio(0);
            if (s < NS - 3)       asm volatile("s_waitcnt vmcnt(8)" ::: "memory");
            else if (s == NS - 3) asm volatile("s_waitcnt vmcnt(4)" ::: "memory");
            else if (s == NS - 2) asm volatile("s_waitcnt vmcnt(0)" ::: "memory");
            __builtin_amdgcn_s_barrier();
        }
    }
}

// ---------------- GEMM1: FUSED -> ab = bf16(exp(S*SCALE*M)); else S f32 ------------
template<bool FUSED>
__global__ __launch_bounds__(256, 2)
void qk4(const unsigned short* __restrict__ Qb, const unsigned short* __restrict__ Kb,
         const float* __restrict__ M, float* __restrict__ S,
         unsigned short* __restrict__ ab) {
    __shared__ __align__(16) unsigned short lA[16384];
    __shared__ __align__(16) unsigned short lB[16384];

    // 2048 blocks: XCD-bijective swizzle (2048 % 8 == 0); one batch per XCD.
    const int l   = blockIdx.x;
    const int swz = (l & 7) * 256 + (l >> 3);
    const int b   = swz >> 8;
    const int my  = (swz >> 4) & 15;
    const int nx  = swz & 15;
    const int q0  = my * 128;
    const int n0  = nx * 128;

    const unsigned short* Ap = Qb + ((size_t)b * LQ  + q0) * DH;
    const unsigned short* Bp = Kb + ((size_t)b * LKK + n0) * DH;

    f32x4 acc[4][4];
    gemm4_mainloop<DH, DH, DH / 32>(Ap, Bp, lA, lB, acc);

    const int lane = threadIdx.x & 63;
    const int wid  = threadIdx.x >> 6;
    const int wm   = (wid & 1) * 64;
    const int wn   = (wid >> 1) * 64;
    const int lrow = lane & 15;
    const int quad = lane >> 4;

    // C/D layout: col = lane&15, row = quad*4 + r (m89/m91)
    const size_t base = (size_t)b * LQ * LKK;
#pragma unroll
    for (int mf = 0; mf < 4; ++mf) {
#pragma unroll
        for (int rr = 0; rr < 4; ++rr) {
            const int row = q0 + wm + mf * 16 + quad * 4 + rr;
            const size_t rb = base + (size_t)row * LKK;
#pragma unroll
            for (int nf = 0; nf < 4; ++nf) {
                const int col = n0 + wn + nf * 16 + lrow;
                if (FUSED) {
                    // e = exp(S'); |S'| <= ~6 so exp is f32-safe without max-sub.
                    const float e = __expf(acc[mf][nf][rr] * SCALE * M[rb + col]);
                    ab[rb + col] = pack_bf16(e);
                } else {
                    S[rb + col] = acc[mf][nf][rr] * SCALE * M[rb + col];
                }
            }
        }
    }
}

// ---------------- sum+normalize: attn = e*inv (f32), inv[row] saved for pk ---------
__global__ __launch_bounds__(256)
void sum_norm(const unsigned short* __restrict__ ab, float* __restrict__ attn,
              float* __restrict__ inv) {
    const int row  = blockIdx.x * 4 + (threadIdx.x >> 6);
    const int lane = threadIdx.x & 63;
    const unsigned short* q = ab + (size_t)row * LKK;

    u32x4 w[4];
#pragma unroll
    for (int i = 0; i < 4; ++i) w[i] = *(const u32x4*)(q + i * 512 + lane * 8);

    float v[32];
    float s = 0.f;
#pragma unroll
    for (int i = 0; i < 4; ++i)
#pragma unroll
        for (int j = 0; j < 4; ++j) {
            const unsigned u = w[i][j];
            const float lo = __builtin_bit_cast(float, u << 16);
            const float hi = __builtin_bit_cast(float, u & 0xFFFF0000u);
            v[i * 8 + j * 2]     = lo;
            v[i * 8 + j * 2 + 1] = hi;
            s += lo + hi;
        }
#pragma unroll
    for (int o = 32; o >= 1; o >>= 1) s += __shfl_xor(s, o, 64);
    const float iv = 1.f / s;

    float* p = attn + (size_t)row * LKK;
#pragma unroll
    for (int i = 0; i < 4; ++i) {
        f32x4 o0, o1;
#pragma unroll
        for (int j = 0; j < 4; ++j) { o0[j] = v[i * 8 + j] * iv; o1[j] = v[i * 8 + 4 + j] * iv; }
        *(f32x4*)(p + i * 512 + lane * 8)     = o0;
        *(f32x4*)(p + i * 512 + lane * 8 + 4) = o1;
    }
    if (lane == 0) inv[row] = iv;
}

// ---------------- legacy softmax (fallback path): normalize f32 in place ----------
__global__ __launch_bounds__(256)
void softmax_kernel(float* __restrict__ A, unsigned short* __restrict__ ab) {
    const int row  = blockIdx.x * 4 + (threadIdx.x >> 6);
    const int lane = threadIdx.x & 63;
    float* p = A + (size_t)row * LKK;

    f32x4 v[8];
#pragma unroll
    for (int i = 0; i < 8; ++i) v[i] = *(const f32x4*)(p + i * 256 + lane * 4);

    float m = v[0][0];
#pragma unroll
    for (int i = 0; i < 8; ++i)
#pragma unroll
        for (int j = 0; j < 4; ++j) m = fmaxf(m, v[i][j]);
#pragma unroll
    for (int o = 32; o >= 1; o >>= 1) m = fmaxf(m, __shfl_xor(m, o, 64));

    float s = 0.f;
#pragma unroll
    for (int i = 0; i < 8; ++i)
#pragma unroll
        for (int j = 0; j < 4; ++j) { v[i][j] = __expf(v[i][j] - m); s += v[i][j]; }
#pragma unroll
    for (int o = 32; o >= 1; o >>= 1) s += __shfl_xor(s, o, 64);
    const float inv = 1.f / s;

#pragma unroll
    for (int i = 0; i < 8; ++i) {
#pragma unroll
        for (int j = 0; j < 4; ++j) v[i][j] *= inv;
        *(f32x4*)(p + i * 256 + lane * 4) = v[i];
    }

    if (ab) {
        unsigned short* q = ab + (size_t)row * LKK;
#pragma unroll
        for (int i = 0; i < 8; ++i) {
            u32x2 w;
            w[0] = pack_bf16x2(v[i][0], v[i][1]);
            w[1] = pack_bf16x2(v[i][2], v[i][3]);
            *(u32x2*)(q + i * 256 + lane * 4) = w;
        }
    }
}

// ---------------- GEMM2: ctx = (e_bf * KT_bf) * inv[row] ---------------------------
__global__ __launch_bounds__(256, 2)
void pk4(const unsigned short* __restrict__ Pb, const unsigned short* __restrict__ KT,
         const float* __restrict__ Inv, float* __restrict__ C) {
    __shared__ __align__(16) unsigned short lA[16384];
    __shared__ __align__(16) unsigned short lB[16384];

    // 1024 blocks: b(8) x my(16) x nx(8), XCD-bijective swizzle (1024 % 8 == 0).
    const int l   = blockIdx.x;
    const int swz = (l & 7) * 128 + (l >> 3);
    const int b   = swz >> 7;
    const int my  = (swz >> 3) & 15;
    const int nx  = swz & 7;
    const int q0  = my * 128;
    const int n0  = nx * 128;   // d offset

    const unsigned short* Ap = Pb + ((size_t)b * LQ + q0) * LKK;
    const unsigned short* Bp = KT + ((size_t)b * DH + n0) * LKK;

    f32x4 acc[4][4];
    gemm4_mainloop<LKK, LKK, LKK / 32>(Ap, Bp, lA, lB, acc);

    const int lane = threadIdx.x & 63;
    const int wid  = threadIdx.x >> 6;
    const int wm   = (wid & 1) * 64;
    const int wn   = (wid >> 1) * 64;
    const int lrow = lane & 15;
    const int quad = lane >> 4;

    const float* Ivp = Inv + (size_t)b * LQ;
    const size_t cb = (size_t)b * LQ * DH;
#pragma unroll
    for (int mf = 0; mf < 4; ++mf) {
#pragma unroll
        for (int rr = 0; rr < 4; ++rr) {
            const int row = q0 + wm + mf * 16 + quad * 4 + rr;
            const float iv = Ivp[row];
            const size_t rbase = cb + (size_t)row * DH;
#pragma unroll
            for (int nf = 0; nf < 4; ++nf)
                C[rbase + n0 + wn + nf * 16 + lrow] = acc[mf][nf][rr] * iv;
        }
    }
}

// ---------------- GEMM2 fallback (128^2 2-phase): inline fp32->bf16 ----------------
constexpr int BM = 128, BN = 128, TK = 32;
constexpr int LDSS = 40;
__global__ __launch_bounds__(256, 2)
void pk_kernel(const float* __restrict__ P, const float* __restrict__ K,
               float* __restrict__ C) {
    __shared__ unsigned short lA[BM * LDSS];
    __shared__ unsigned short lB[BN * LDSS];

    const int b  = blockIdx.z;
    const int q0 = blockIdx.y * BM;
    const int n0 = blockIdx.x * BN;
    const float* Pp = P + (size_t)b * LQ * LKK + (size_t)q0 * LKK;
    const float* Kb = K + (size_t)b * LKK * DH;

    const int tid  = threadIdx.x;
    const int lane = tid & 63;
    const int wid  = tid >> 6;
    const int wm   = (wid & 1) * 64;
    const int wn   = (wid >> 1) * 64;
    const int lrow = lane & 15;
    const int quad = lane >> 4;

    f32x4 acc[4][4];
#pragma unroll
    for (int i = 0; i < 4; ++i)
#pragma unroll
        for (int j = 0; j < 4; ++j) acc[i][j] = (f32x4){0.f, 0.f, 0.f, 0.f};

    const int srow = tid >> 3;
    const int skq  = (tid & 7) << 2;
    const int tdb  = tid >> 3;
    const int tkb  = tid & 7;

    for (int k0 = 0; k0 < LKK; k0 += TK) {
        __syncthreads();
#pragma unroll
        for (int i = 0; i < 4; ++i) {
            const int row = i * 32 + srow;
            const f32x4 va = *(const f32x4*)(Pp + (size_t)row * LKK + k0 + skq);
            unsigned* pa = (unsigned*)&lA[row * LDSS + skq];
            pa[0] = pack_bf16x2(va[0], va[1]);
            pa[1] = pack_bf16x2(va[2], va[3]);
        }
        f32x4 rk[4];
#pragma unroll
        for (int j = 0; j < 4; ++j)
            rk[j] = *(const f32x4*)(Kb + (size_t)(k0 + tkb * 4 + j) * DH + n0 + tdb * 4);
#pragma unroll
        for (int c = 0; c < 4; ++c) {
            unsigned* pb = (unsigned*)&lB[(tdb * 4 + c) * LDSS + tkb * 4];
            pb[0] = pack_bf16x2(rk[0][c], rk[1][c]);
            pb[1] = pack_bf16x2(rk[2][c], rk[3][c]);
        }
        __syncthreads();

        bf16x8 af[4], bfr[4];
#pragma unroll
        for (int i = 0; i < 4; ++i) {
            af[i]  = *(const bf16x8*)&lA[(wm + i * 16 + lrow) * LDSS + quad * 8];
            bfr[i] = *(const bf16x8*)&lB[(wn + i * 16 + lrow) * LDSS + quad * 8];
        }
#pragma unroll
        for (int i = 0; i < 4; ++i)
#pragma unroll
            for (int j = 0; j < 4; ++j)
                acc[i][j] = __builtin_amdgcn_mfma_f32_16x16x32_bf16(af[i], bfr[j], acc[i][j], 0, 0, 0);
    }

    const size_t cb = (size_t)b * LQ * DH;
#pragma unroll
    for (int i = 0; i < 4; ++i) {
#pragma unroll
        for (int r = 0; r < 4; ++r) {
            const int row = q0 + wm + i * 16 + quad * 4 + r;
            const size_t rbase = cb + (size_t)row * DH;
#pragma unroll
            for (int j = 0; j < 4; ++j)
                C[rbase + n0 + wn + j * 16 + lrow] = acc[i][j][r];
        }
    }
}

extern "C" void kernel_launch(void* const* d_in, const int* in_sizes, int n_in,
                              void* d_out, int out_size, void* d_ws, size_t ws_size,
                              hipStream_t stream) {
    const float* Q = (const float*)d_in[0];
    const float* K = (const float*)d_in[1];
    const float* M = (const float*)d_in[2];

    constexpr size_t QEL  = (size_t)BATCH * LQ * DH;    // 16,777,216 (ctx elems)
    constexpr size_t AEL  = (size_t)BATCH * LQ * LKK;   // 33,554,432 (attn elems)
    constexpr size_t KTEL = (size_t)BATCH * DH * LKK;   // 16,777,216
    constexpr size_t REL  = (size_t)BATCH * LQ;         // 16,384 row sums

    float* ctx  = (float*)d_out;
    float* attn = ctx + QEL;

    // bf16 Q/K scratch inside the (not-yet-written) ctx region: 2*QEL*2B == QEL*4B.
    unsigned short* Qb = (unsigned short*)ctx;
    unsigned short* Kb = Qb + QEL;

    const bool wsOK = ws_size >= (KTEL + AEL) * sizeof(unsigned short)
                               + REL * sizeof(float);
    unsigned short* KT = (unsigned short*)d_ws;
    unsigned short* ab = KT + KTEL;
    float* inv = (float*)(ab + AEL);

    if (wsOK) {
        cvt_kernel<<<dim3(4096), 256, 0, stream>>>(Q, K, Qb, Kb);   // Q only
        kt_kernel<<<dim3(DH / 64, LKK / 64, BATCH), 256, 0, stream>>>(K, KT, Kb);
        qk4<true><<<dim3(BATCH * (LQ / 128) * (LKK / 128)), 256, 0, stream>>>(
            Qb, Kb, M, nullptr, ab);
        sum_norm<<<dim3(BATCH * LQ / 4), 256, 0, stream>>>(ab, attn, inv);
        pk4<<<dim3(BATCH * (LQ / 128) * (DH / 128)), 256, 0, stream>>>(ab, KT, inv, ctx);
    } else {
        cvt_kernel<<<dim3(8192), 256, 0, stream>>>(Q, K, Qb, Kb);   // Q and K
        qk4<false><<<dim3(BATCH * (LQ / 128) * (LKK / 128)), 256, 0, stream>>>(
            Qb, Kb, M, attn, nullptr);
        softmax_kernel<<<dim3(BATCH * LQ / 4), 256, 0, stream>>>(attn, nullptr);
        pk_kernel<<<dim3(DH / BN, LQ / BM, BATCH), 256, 0, stream>>>(attn, K, ctx);
    }
}

// Round 7
// 547.293 us; speedup vs baseline: 1.0396x; 1.0396x over previous
//
#include <hip/hip_runtime.h>
#include <hip/hip_bf16.h>

// S = (Q K^T)/32 * mask (multiplicative), attn = softmax(S), ctx = attn * K.
// d_out = ctx (8*2048*1024 f32) ++ attn (8*2048*2048 f32).
// R9 = R6 memory path (fused exp epilogue, sum_norm, single K read) with the
// GEMM mainloop switched from 16x16x32 to 32x32x16 MFMA: same 256x256 BK=64
// tile, same LDS layout/swizzle/staging, but 2 phases per K-tile instead of 4
// (16 MFMA of 32x32 per phase) -> half the barrier pairs and lgkm drains.
// R7/R8's 128^2 TLP experiment refuted and reverted.

typedef __attribute__((ext_vector_type(8)))  short bf16x8;
typedef __attribute__((ext_vector_type(4)))  float f32x4;
typedef __attribute__((ext_vector_type(16))) float f32x16;
typedef __attribute__((ext_vector_type(4)))  unsigned u32x4;
typedef __attribute__((ext_vector_type(2)))  unsigned u32x2;

constexpr int BATCH = 8;
constexpr int LQ    = 2048;
constexpr int LKK   = 2048;
constexpr int DH    = 1024;
constexpr float SCALE = 0.03125f;   // 1/sqrt(1024)

#define GAS(p) ((const __attribute__((address_space(1))) void*)(p))
#define LAS(p) ((__attribute__((address_space(3))) void*)(p))

// 32-bit LDS byte offset of a generic pointer into __shared__
__device__ __forceinline__ unsigned lds_addr(const unsigned short* p) {
    return (unsigned)(unsigned long long)
        (const __attribute__((address_space(3))) unsigned short*)p;
}

// opaque LDS read (rule 18: caller waits lgkmcnt + sched_barrier(0) before use)
__device__ __forceinline__ bf16x8 dsr_b128(unsigned off) {
    bf16x8 r;
    asm volatile("ds_read_b128 %0, %1" : "=v"(r) : "v"(off));
    return r;
}

// round-half-up fp32->bf16 pair pack (2 adds + v_perm)
__device__ __forceinline__ unsigned pack_bf16x2(float x0, float x1) {
    unsigned a = __builtin_bit_cast(unsigned, x0) + 0x8000u;
    unsigned b = __builtin_bit_cast(unsigned, x1) + 0x8000u;
    return __builtin_amdgcn_perm(b, a, 0x07060302u);  // mem order: x0.hi16, x1.hi16
}

__device__ __forceinline__ unsigned short pack_bf16(float x) {
    return (unsigned short)((__builtin_bit_cast(unsigned, x) + 0x8000u) >> 16);
}

// ---------------- prep: Q (and K if fallback) fp32 -> bf16 ------------------------
__global__ __launch_bounds__(256)
void cvt_kernel(const float* __restrict__ Q, const float* __restrict__ K,
                unsigned short* __restrict__ Qb, unsigned short* __restrict__ Kb) {
    const int bid = blockIdx.x;
    const float* src; unsigned short* dst; size_t off;
    if (bid < 4096) { src = Q; dst = Qb; off = (size_t)bid * 4096; }
    else            { src = K; dst = Kb; off = (size_t)(bid - 4096) * 4096; }
    off += (size_t)threadIdx.x * 16;
    const f32x4 a = *(const f32x4*)(src + off);
    const f32x4 b = *(const f32x4*)(src + off + 4);
    const f32x4 c = *(const f32x4*)(src + off + 8);
    const f32x4 d = *(const f32x4*)(src + off + 12);
    u32x4 v0, v1;
    v0[0] = pack_bf16x2(a[0], a[1]); v0[1] = pack_bf16x2(a[2], a[3]);
    v0[2] = pack_bf16x2(b[0], b[1]); v0[3] = pack_bf16x2(b[2], b[3]);
    v1[0] = pack_bf16x2(c[0], c[1]); v1[1] = pack_bf16x2(c[2], c[3]);
    v1[2] = pack_bf16x2(d[0], d[1]); v1[3] = pack_bf16x2(d[2], d[3]);
    *(u32x4*)(dst + off)     = v0;
    *(u32x4*)(dst + off + 8) = v1;
}

// ---------------- prep: K fp32 -> K^T bf16 (LDS transpose) AND row-major Kb -------
__global__ __launch_bounds__(256)
void kt_kernel(const float* __restrict__ K, unsigned short* __restrict__ KT,
               unsigned short* __restrict__ Kb) {
    __shared__ unsigned short T[64 * 68];
    const int b  = blockIdx.z;
    const int k0 = blockIdx.y * 64;
    const int d0 = blockIdx.x * 64;
    const int t  = threadIdx.x;
    const int k4 = (t >> 4) * 4;
    const int d4 = (t & 15) * 4;
    f32x4 rk[4];
    const float* Kp = K + ((size_t)b * LKK + k0 + k4) * DH + d0 + d4;
#pragma unroll
    for (int j = 0; j < 4; ++j) rk[j] = *(const f32x4*)(Kp + (size_t)j * DH);
    unsigned short* Kbp = Kb + ((size_t)b * LKK + k0 + k4) * DH + d0 + d4;
#pragma unroll
    for (int j = 0; j < 4; ++j) {
        u32x2 w;
        w[0] = pack_bf16x2(rk[j][0], rk[j][1]);
        w[1] = pack_bf16x2(rk[j][2], rk[j][3]);
        *(u32x2*)(Kbp + (size_t)j * DH) = w;
    }
#pragma unroll
    for (int c = 0; c < 4; ++c) {
        u32x2 w;
        w[0] = pack_bf16x2(rk[0][c], rk[1][c]);
        w[1] = pack_bf16x2(rk[2][c], rk[3][c]);
        *(u32x2*)&T[(d4 + c) * 68 + k4] = w;
    }
    __syncthreads();
    const int d  = t >> 2;
    const int kc = (t & 3) * 16;
    u32x2 a0 = *(const u32x2*)&T[d * 68 + kc];
    u32x2 a1 = *(const u32x2*)&T[d * 68 + kc + 4];
    u32x2 a2 = *(const u32x2*)&T[d * 68 + kc + 8];
    u32x2 a3 = *(const u32x2*)&T[d * 68 + kc + 12];
    unsigned short* dst = KT + ((size_t)b * DH + d0 + d) * LKK + k0 + kc;
    u32x4 w0; w0[0] = a0[0]; w0[1] = a0[1]; w0[2] = a1[0]; w0[3] = a1[1];
    u32x4 w1; w1[0] = a2[0]; w1[1] = a2[1]; w1[2] = a3[0]; w1[3] = a3[1];
    *(u32x4*)dst       = w0;
    *(u32x4*)(dst + 8) = w1;
}

// ============ 256x256 BK=64 mainloop, 32x32x16 MFMA, 2 phases/K-tile (R9) ==========
// LDS per matrix: [2 parity][2 khalf][256 rows][32 k bf16] = 64 KiB; total 128 KiB.
// 8 waves (2M x 4N): wave-tile 128x64 = 4 mf (32 rows) x 2 nf (32 cols).
// Fragments (32x32x16): A/B lane l: row/col = l&31, k = (l>>5)*8 + j.
//                       C/D lane l: col = l&31, row = (r&3)+8*(r>>2)+4*(l>>5)  [m74/m101].
// Phase p = 2T+q (q = khalf). Per phase: 12 ds_read_b128 (A 4mf x 2 k16-slices,
// B 2nf x 2), stage 2 half-tiles (halves 2p+6, 2p+7), 16 MFMA of 32x32x16.
// vmcnt (2 instr per stage call): steady in-flight 6 calls = 12 instr, retire 2
// calls/phase -> vmcnt(8); issue->wait slack = 3 phases.
//   RAW: end of phase p, vmcnt(8) leaves calls 2p+4..2p+7 in flight -> halves
//        2p+2, 2p+3 (= phase p+1's reads) landed before its reads.
//   prologue: stage halves 0..5 (12 instr), vmcnt(8) -> halves 0,1 landed.
//   tail: p==2NT-3 -> vmcnt(4); p==2NT-2 -> vmcnt(0); p==2NT-1 -> none.
//   WAR: stage at phase p overwrites a region whose last reads drained at the
//        previous phase's lgkmcnt(0), >=1 end-barrier earlier.
// Chunk swizzle: 16B chunk c of row r at slot c ^ ((r>>1)&3); write side realized
// by pre-swizzling the GLOBAL source column (gload_lds dest stays linear).
// Read chunk = s*2 + (lane>>5); per 16-lane group banks repeat 2-way = free (m136).
template<int LDA, int LDB, int NT>
__device__ __forceinline__ void gemm32_mainloop(
    const unsigned short* __restrict__ Ab,
    const unsigned short* __restrict__ Bb,
    unsigned short* lA, unsigned short* lB,
    f32x16 (&acc)[4][2])
{
    const int tid  = threadIdx.x;
    const int lane = tid & 63;
    const int wid  = tid >> 6;
    const int wm   = (wid & 1) * 128;
    const int wn   = (wid >> 1) * 64;
    const int l31  = lane & 31;
    const int lhi  = lane >> 5;                              // k-subgroup (0/1)

    const int srow0 = wid * 32 + (lane >> 2);
    const int srow1 = srow0 + 16;
    const int sc    = ((lane & 3) ^ ((lane >> 3) & 3)) * 8;  // pre-swizzled source col

    auto stage = [&](int I) {
        if (I >= 4 * NT) return;
        const int tile = I >> 2;
        const int h    = I & 3;
        const int kh   = h >> 1;
        const int kb   = tile * 64 + kh * 32 + sc;
        const unsigned short* s = (h & 1) ? Bb : Ab;
        const int ld            = (h & 1) ? LDB : LDA;
        unsigned short* d = ((h & 1) ? lB : lA)
                          + (tile & 1) * 16384 + kh * 8192 + wid * 1024;
        __builtin_amdgcn_global_load_lds(GAS(s + (size_t)srow0 * ld + kb), LAS(d),       16, 0, 0);
        __builtin_amdgcn_global_load_lds(GAS(s + (size_t)srow1 * ld + kb), LAS(d + 512), 16, 0, 0);
    };

    // swizzled read address for a 32-row fragment, k16-slice s
    auto raddr = [&](int base, int row, int s) {
        const int chunk = s * 2 + lhi;
        const int slot  = chunk ^ ((row >> 1) & 3);
        return base + row * 32 + slot * 8;
    };

#pragma unroll
    for (int i = 0; i < 4; ++i)
#pragma unroll
        for (int j = 0; j < 2; ++j)
#pragma unroll
            for (int e = 0; e < 16; ++e) acc[i][j][e] = 0.f;

    // prologue: tile0 complete + tile1 kh0 in flight
#pragma unroll
    for (int I = 0; I < 6; ++I) stage(I);
    asm volatile("s_waitcnt vmcnt(8)" ::: "memory");
    __builtin_amdgcn_s_barrier();

    auto tilebody = [&](int T, int par) {
#pragma unroll
        for (int q = 0; q < 2; ++q) {
            const int p    = 2 * T + q;
            const int base = par + q * 8192;
            bf16x8 af[4][2], bfr[2][2];
#pragma unroll
            for (int s = 0; s < 2; ++s) {
#pragma unroll
                for (int nf = 0; nf < 2; ++nf)
                    bfr[nf][s] = dsr_b128(lds_addr(&lB[raddr(base, wn + nf * 32 + l31, s)]));
#pragma unroll
                for (int mf = 0; mf < 4; ++mf)
                    af[mf][s] = dsr_b128(lds_addr(&lA[raddr(base, wm + mf * 32 + l31, s)]));
            }

            stage(2 * p + 6);
            stage(2 * p + 7);

            __builtin_amdgcn_s_barrier();
            asm volatile("s_waitcnt lgkmcnt(0)" ::: "memory");
            __builtin_amdgcn_sched_barrier(0);
            __builtin_amdgcn_s_setprio(1);
#pragma unroll
            for (int s = 0; s < 2; ++s)
#pragma unroll
                for (int mf = 0; mf < 4; ++mf)
#pragma unroll
                    for (int nf = 0; nf < 2; ++nf)
                        acc[mf][nf] = __builtin_amdgcn_mfma_f32_32x32x16_bf16(
                            af[mf][s], bfr[nf][s], acc[mf][nf], 0, 0, 0);
            __builtin_amdgcn_s_setprio(0);
            if (p < 2 * NT - 3)       asm volatile("s_waitcnt vmcnt(8)" ::: "memory");
            else if (p == 2 * NT - 3) asm volatile("s_waitcnt vmcnt(4)" ::: "memory");
            else if (p == 2 * NT - 2) asm volatile("s_waitcnt vmcnt(0)" ::: "memory");
            __builtin_amdgcn_s_barrier();
        }
    };

    for (int T = 0; T < NT; T += 2) {   // NT even; compile-time LDS parity
        tilebody(T,     0);
        tilebody(T + 1, 16384);
    }
}

// ---------------- GEMM1: FUSED -> ab = bf16(exp(S*SCALE*M)); else S f32 ------------
template<bool FUSED>
__global__ __launch_bounds__(512, 2)
void qk8(const unsigned short* __restrict__ Qb, const unsigned short* __restrict__ Kb,
         const float* __restrict__ M, float* __restrict__ S,
         unsigned short* __restrict__ ab) {
    __shared__ __align__(16) unsigned short lA[32768];
    __shared__ __align__(16) unsigned short lB[32768];

    // 512 blocks: XCD-bijective swizzle (512 % 8 == 0); each XCD chunk = one batch.
    const int l   = blockIdx.x;
    const int swz = (l & 7) * 64 + (l >> 3);
    const int b   = swz >> 6;
    const int my  = (swz >> 3) & 7;
    const int nx  = swz & 7;
    const int q0  = my * 256;
    const int n0  = nx * 256;

    const unsigned short* Ap = Qb + ((size_t)b * LQ  + q0) * DH;
    const unsigned short* Bp = Kb + ((size_t)b * LKK + n0) * DH;

    f32x16 acc[4][2];
    gemm32_mainloop<DH, DH, DH / 64>(Ap, Bp, lA, lB, acc);

    const int lane = threadIdx.x & 63;
    const int wid  = threadIdx.x >> 6;
    const int wm   = (wid & 1) * 128;
    const int wn   = (wid >> 1) * 64;
    const int l31  = lane & 31;
    const int lhi  = lane >> 5;

    // C/D 32x32: col = lane&31, row = (r&3) + 8*(r>>2) + 4*(lane>>5)  [m74/m101]
    const size_t base = (size_t)b * LQ * LKK;
#pragma unroll
    for (int mf = 0; mf < 4; ++mf) {
#pragma unroll
        for (int r = 0; r < 16; ++r) {
            const int row = q0 + wm + mf * 32 + (r & 3) + 8 * (r >> 2) + 4 * lhi;
            const size_t rb = base + (size_t)row * LKK;
#pragma unroll
            for (int nf = 0; nf < 2; ++nf) {
                const int col = n0 + wn + nf * 32 + l31;
                if (FUSED) {
                    // e = exp(S'); |S'| <= ~6 so exp is f32-safe without max-sub.
                    const float e = __expf(acc[mf][nf][r] * SCALE * M[rb + col]);
                    ab[rb + col] = pack_bf16(e);
                } else {
                    S[rb + col] = acc[mf][nf][r] * SCALE * M[rb + col];
                }
            }
        }
    }
}

// ---------------- sum+normalize: attn = e*inv (f32), inv[row] saved for pk ---------
__global__ __launch_bounds__(256)
void sum_norm(const unsigned short* __restrict__ ab, float* __restrict__ attn,
              float* __restrict__ inv) {
    const int row  = blockIdx.x * 4 + (threadIdx.x >> 6);
    const int lane = threadIdx.x & 63;
    const unsigned short* q = ab + (size_t)row * LKK;

    u32x4 w[4];
#pragma unroll
    for (int i = 0; i < 4; ++i) w[i] = *(const u32x4*)(q + i * 512 + lane * 8);

    float v[32];
    float s = 0.f;
#pragma unroll
    for (int i = 0; i < 4; ++i)
#pragma unroll
        for (int j = 0; j < 4; ++j) {
            const unsigned u = w[i][j];
            const float lo = __builtin_bit_cast(float, u << 16);
            const float hi = __builtin_bit_cast(float, u & 0xFFFF0000u);
            v[i * 8 + j * 2]     = lo;
            v[i * 8 + j * 2 + 1] = hi;
            s += lo + hi;
        }
#pragma unroll
    for (int o = 32; o >= 1; o >>= 1) s += __shfl_xor(s, o, 64);
    const float iv = 1.f / s;

    float* p = attn + (size_t)row * LKK;
#pragma unroll
    for (int i = 0; i < 4; ++i) {
        f32x4 o0, o1;
#pragma unroll
        for (int j = 0; j < 4; ++j) { o0[j] = v[i * 8 + j] * iv; o1[j] = v[i * 8 + 4 + j] * iv; }
        *(f32x4*)(p + i * 512 + lane * 8)     = o0;
        *(f32x4*)(p + i * 512 + lane * 8 + 4) = o1;
    }
    if (lane == 0) inv[row] = iv;
}

// ---------------- legacy softmax (fallback path): normalize f32 in place ----------
__global__ __launch_bounds__(256)
void softmax_kernel(float* __restrict__ A, unsigned short* __restrict__ ab) {
    const int row  = blockIdx.x * 4 + (threadIdx.x >> 6);
    const int lane = threadIdx.x & 63;
    float* p = A + (size_t)row * LKK;

    f32x4 v[8];
#pragma unroll
    for (int i = 0; i < 8; ++i) v[i] = *(const f32x4*)(p + i * 256 + lane * 4);

    float m = v[0][0];
#pragma unroll
    for (int i = 0; i < 8; ++i)
#pragma unroll
        for (int j = 0; j < 4; ++j) m = fmaxf(m, v[i][j]);
#pragma unroll
    for (int o = 32; o >= 1; o >>= 1) m = fmaxf(m, __shfl_xor(m, o, 64));

    float s = 0.f;
#pragma unroll
    for (int i = 0; i < 8; ++i)
#pragma unroll
        for (int j = 0; j < 4; ++j) { v[i][j] = __expf(v[i][j] - m); s += v[i][j]; }
#pragma unroll
    for (int o = 32; o >= 1; o >>= 1) s += __shfl_xor(s, o, 64);
    const float inv = 1.f / s;

#pragma unroll
    for (int i = 0; i < 8; ++i) {
#pragma unroll
        for (int j = 0; j < 4; ++j) v[i][j] *= inv;
        *(f32x4*)(p + i * 256 + lane * 4) = v[i];
    }

    if (ab) {
        unsigned short* q = ab + (size_t)row * LKK;
#pragma unroll
        for (int i = 0; i < 8; ++i) {
            u32x2 w;
            w[0] = pack_bf16x2(v[i][0], v[i][1]);
            w[1] = pack_bf16x2(v[i][2], v[i][3]);
            *(u32x2*)(q + i * 256 + lane * 4) = w;
        }
    }
}

// ---------------- GEMM2: ctx = (e_bf * KT_bf) * inv[row] ---------------------------
__global__ __launch_bounds__(512, 2)
void pk8(const unsigned short* __restrict__ Pb, const unsigned short* __restrict__ KT,
         const float* __restrict__ Inv, float* __restrict__ C) {
    __shared__ __align__(16) unsigned short lA[32768];
    __shared__ __align__(16) unsigned short lB[32768];

    // 256 blocks: b(8) x my(8) x nx(4), XCD-bijective swizzle (256 % 8 == 0).
    const int l   = blockIdx.x;
    const int swz = (l & 7) * 32 + (l >> 3);
    const int b   = swz >> 5;
    const int my  = (swz >> 2) & 7;
    const int nx  = swz & 3;
    const int q0  = my * 256;
    const int n0  = nx * 256;   // d offset

    const unsigned short* Ap = Pb + ((size_t)b * LQ + q0) * LKK;
    const unsigned short* Bp = KT + ((size_t)b * DH + n0) * LKK;

    f32x16 acc[4][2];
    gemm32_mainloop<LKK, LKK, LKK / 64>(Ap, Bp, lA, lB, acc);

    const int lane = threadIdx.x & 63;
    const int wid  = threadIdx.x >> 6;
    const int wm   = (wid & 1) * 128;
    const int wn   = (wid >> 1) * 64;
    const int l31  = lane & 31;
    const int lhi  = lane >> 5;

    const float* Ivp = Inv + (size_t)b * LQ;
    const size_t cb = (size_t)b * LQ * DH;
#pragma unroll
    for (int mf = 0; mf < 4; ++mf) {
#pragma unroll
        for (int r = 0; r < 16; ++r) {
            const int row = q0 + wm + mf * 32 + (r & 3) + 8 * (r >> 2) + 4 * lhi;
            const float iv = Ivp[row];
            const size_t rbase = cb + (size_t)row * DH;
#pragma unroll
            for (int nf = 0; nf < 2; ++nf)
                C[rbase + n0 + wn + nf * 32 + l31] = acc[mf][nf][r] * iv;
        }
    }
}

// ---------------- GEMM2 fallback (128^2 2-phase): inline fp32->bf16 ----------------
constexpr int BM = 128, BN = 128, TK = 32;
constexpr int LDSS = 40;
__global__ __launch_bounds__(256, 2)
void pk_kernel(const float* __restrict__ P, const float* __restrict__ K,
               float* __restrict__ C) {
    __shared__ unsigned short lA[BM * LDSS];
    __shared__ unsigned short lB[BN * LDSS];

    const int b  = blockIdx.z;
    const int q0 = blockIdx.y * BM;
    const int n0 = blockIdx.x * BN;
    const float* Pp = P + (size_t)b * LQ * LKK + (size_t)q0 * LKK;
    const float* Kb = K + (size_t)b * LKK * DH;

    const int tid  = threadIdx.x;
    const int lane = tid & 63;
    const int wid  = tid >> 6;
    const int wm   = (wid & 1) * 64;
    const int wn   = (wid >> 1) * 64;
    const int lrow = lane & 15;
    const int quad = lane >> 4;

    f32x4 acc[4][4];
#pragma unroll
    for (int i = 0; i < 4; ++i)
#pragma unroll
        for (int j = 0; j < 4; ++j) acc[i][j] = (f32x4){0.f, 0.f, 0.f, 0.f};

    const int srow = tid >> 3;
    const int skq  = (tid & 7) << 2;
    const int tdb  = tid >> 3;
    const int tkb  = tid & 7;

    for (int k0 = 0; k0 < LKK; k0 += TK) {
        __syncthreads();
#pragma unroll
        for (int i = 0; i < 4; ++i) {
            const int row = i * 32 + srow;
            const f32x4 va = *(const f32x4*)(Pp + (size_t)row * LKK + k0 + skq);
            unsigned* pa = (unsigned*)&lA[row * LDSS + skq];
            pa[0] = pack_bf16x2(va[0], va[1]);
            pa[1] = pack_bf16x2(va[2], va[3]);
        }
        f32x4 rk[4];
#pragma unroll
        for (int j = 0; j < 4; ++j)
            rk[j] = *(const f32x4*)(Kb + (size_t)(k0 + tkb * 4 + j) * DH + n0 + tdb * 4);
#pragma unroll
        for (int c = 0; c < 4; ++c) {
            unsigned* pb = (unsigned*)&lB[(tdb * 4 + c) * LDSS + tkb * 4];
            pb[0] = pack_bf16x2(rk[0][c], rk[1][c]);
            pb[1] = pack_bf16x2(rk[2][c], rk[3][c]);
        }
        __syncthreads();

        bf16x8 af[4], bfr[4];
#pragma unroll
        for (int i = 0; i < 4; ++i) {
            af[i]  = *(const bf16x8*)&lA[(wm + i * 16 + lrow) * LDSS + quad * 8];
            bfr[i] = *(const bf16x8*)&lB[(wn + i * 16 + lrow) * LDSS + quad * 8];
        }
#pragma unroll
        for (int i = 0; i < 4; ++i)
#pragma unroll
            for (int j = 0; j < 4; ++j)
                acc[i][j] = __builtin_amdgcn_mfma_f32_16x16x32_bf16(af[i], bfr[j], acc[i][j], 0, 0, 0);
    }

    const size_t cb = (size_t)b * LQ * DH;
#pragma unroll
    for (int i = 0; i < 4; ++i) {
#pragma unroll
        for (int r = 0; r < 4; ++r) {
            const int row = q0 + wm + i * 16 + quad * 4 + r;
            const size_t rbase = cb + (size_t)row * DH;
#pragma unroll
            for (int j = 0; j < 4; ++j)
                C[rbase + n0 + wn + j * 16 + lrow] = acc[i][j][r];
        }
    }
}

extern "C" void kernel_launch(void* const* d_in, const int* in_sizes, int n_in,
                              void* d_out, int out_size, void* d_ws, size_t ws_size,
                              hipStream_t stream) {
    const float* Q = (const float*)d_in[0];
    const float* K = (const float*)d_in[1];
    const float* M = (const float*)d_in[2];

    constexpr size_t QEL  = (size_t)BATCH * LQ * DH;    // 16,777,216 (ctx elems)
    constexpr size_t AEL  = (size_t)BATCH * LQ * LKK;   // 33,554,432 (attn elems)
    constexpr size_t KTEL = (size_t)BATCH * DH * LKK;   // 16,777,216
    constexpr size_t REL  = (size_t)BATCH * LQ;         // 16,384 row sums

    float* ctx  = (float*)d_out;
    float* attn = ctx + QEL;

    // bf16 Q/K scratch inside the (not-yet-written) ctx region: 2*QEL*2B == QEL*4B.
    unsigned short* Qb = (unsigned short*)ctx;
    unsigned short* Kb = Qb + QEL;

    const bool wsOK = ws_size >= (KTEL + AEL) * sizeof(unsigned short)
                               + REL * sizeof(float);
    unsigned short* KT = (unsigned short*)d_ws;
    unsigned short* ab = KT + KTEL;
    float* inv = (float*)(ab + AEL);

    if (wsOK) {
        cvt_kernel<<<dim3(4096), 256, 0, stream>>>(Q, K, Qb, Kb);   // Q only
        kt_kernel<<<dim3(DH / 64, LKK / 64, BATCH), 256, 0, stream>>>(K, KT, Kb);
        qk8<true><<<dim3(BATCH * (LQ / 256) * (LKK / 256)), 512, 0, stream>>>(
            Qb, Kb, M, nullptr, ab);
        sum_norm<<<dim3(BATCH * LQ / 4), 256, 0, stream>>>(ab, attn, inv);
        pk8<<<dim3(BATCH * (LQ / 256) * (DH / 256)), 512, 0, stream>>>(ab, KT, inv, ctx);
    } else {
        cvt_kernel<<<dim3(8192), 256, 0, stream>>>(Q, K, Qb, Kb);   // Q and K
        qk8<false><<<dim3(BATCH * (LQ / 256) * (LKK / 256)), 512, 0, stream>>>(
            Qb, Kb, M, attn, nullptr);
        softmax_kernel<<<dim3(BATCH * LQ / 4), 256, 0, stream>>>(attn, nullptr);
        pk_kernel<<<dim3(DH / BN, LQ / BM, BATCH), 256, 0, stream>>>(attn, K, ctx);
    }
}

// Round 8
// 542.113 us; speedup vs baseline: 1.0496x; 1.0096x over previous
//
#include <hip/hip_runtime.h>
#include <hip/hip_bf16.h>

// S = (Q K^T)/32 * mask (multiplicative), attn = softmax(S), ctx = attn * K.
// d_out = ctx (8*2048*1024 f32) ++ attn (8*2048*2048 f32).
// R10 = R6 (best-measured) with sum_norm ELIMINATED:
//   - qk8 accumulates f32 row-sums via shfl-reduce + global atomicAdd (rowsum
//     zeroed by cvt each iteration).
//   - pk8 writes attn f32 in-loop: block nx owns attn cols [nx*512,(nx+1)*512);
//     after MFMA of its K-tiles it reads back its own staged A-chunks from LDS
//     (linear addr, intra-wave ordered), unpacks, multiplies by inv, stores.
//   - inv = 1/rowsum computed inline in pk8.
// GEMM mainloop byte-identical to R6 (R9's 32x32 variant was neutral; R4/R5/R8
// schedule experiments flat-to-negative — core frozen).

typedef __attribute__((ext_vector_type(8))) short bf16x8;
typedef __attribute__((ext_vector_type(4))) float f32x4;
typedef __attribute__((ext_vector_type(4))) unsigned u32x4;
typedef __attribute__((ext_vector_type(2))) unsigned u32x2;

constexpr int BATCH = 8;
constexpr int LQ    = 2048;
constexpr int LKK   = 2048;
constexpr int DH    = 1024;
constexpr float SCALE = 0.03125f;   // 1/sqrt(1024)

#define GAS(p) ((const __attribute__((address_space(1))) void*)(p))
#define LAS(p) ((__attribute__((address_space(3))) void*)(p))

// 32-bit LDS byte offset of a generic pointer into __shared__
__device__ __forceinline__ unsigned lds_addr(const unsigned short* p) {
    return (unsigned)(unsigned long long)
        (const __attribute__((address_space(3))) unsigned short*)p;
}

// opaque LDS read (rule 18: caller waits lgkmcnt + sched_barrier(0) before use)
__device__ __forceinline__ bf16x8 dsr_b128(unsigned off) {
    bf16x8 r;
    asm volatile("ds_read_b128 %0, %1" : "=v"(r) : "v"(off));
    return r;
}

// round-half-up fp32->bf16 pair pack (2 adds + v_perm)
__device__ __forceinline__ unsigned pack_bf16x2(float x0, float x1) {
    unsigned a = __builtin_bit_cast(unsigned, x0) + 0x8000u;
    unsigned b = __builtin_bit_cast(unsigned, x1) + 0x8000u;
    return __builtin_amdgcn_perm(b, a, 0x07060302u);  // mem order: x0.hi16, x1.hi16
}

__device__ __forceinline__ unsigned short pack_bf16(float x) {
    return (unsigned short)((__builtin_bit_cast(unsigned, x) + 0x8000u) >> 16);
}

// ---------------- prep: Q fp32 -> bf16 (+ zero rowsum); K too in fallback ---------
__global__ __launch_bounds__(256)
void cvt_kernel(const float* __restrict__ Q, const float* __restrict__ K,
                unsigned short* __restrict__ Qb, unsigned short* __restrict__ Kb,
                float* __restrict__ Rs) {
    const int bid = blockIdx.x;
    if (Rs && bid < 16)
        ((f32x4*)Rs)[bid * 256 + threadIdx.x] = (f32x4){0.f, 0.f, 0.f, 0.f};
    const float* src; unsigned short* dst; size_t off;
    if (bid < 4096) { src = Q; dst = Qb; off = (size_t)bid * 4096; }
    else            { src = K; dst = Kb; off = (size_t)(bid - 4096) * 4096; }
    off += (size_t)threadIdx.x * 16;
    const f32x4 a = *(const f32x4*)(src + off);
    const f32x4 b = *(const f32x4*)(src + off + 4);
    const f32x4 c = *(const f32x4*)(src + off + 8);
    const f32x4 d = *(const f32x4*)(src + off + 12);
    u32x4 v0, v1;
    v0[0] = pack_bf16x2(a[0], a[1]); v0[1] = pack_bf16x2(a[2], a[3]);
    v0[2] = pack_bf16x2(b[0], b[1]); v0[3] = pack_bf16x2(b[2], b[3]);
    v1[0] = pack_bf16x2(c[0], c[1]); v1[1] = pack_bf16x2(c[2], c[3]);
    v1[2] = pack_bf16x2(d[0], d[1]); v1[3] = pack_bf16x2(d[2], d[3]);
    *(u32x4*)(dst + off)     = v0;
    *(u32x4*)(dst + off + 8) = v1;
}

// ---------------- prep: K fp32 -> K^T bf16 (LDS transpose) AND row-major Kb -------
__global__ __launch_bounds__(256)
void kt_kernel(const float* __restrict__ K, unsigned short* __restrict__ KT,
               unsigned short* __restrict__ Kb) {
    __shared__ unsigned short T[64 * 68];
    const int b  = blockIdx.z;
    const int k0 = blockIdx.y * 64;
    const int d0 = blockIdx.x * 64;
    const int t  = threadIdx.x;
    const int k4 = (t >> 4) * 4;
    const int d4 = (t & 15) * 4;
    f32x4 rk[4];
    const float* Kp = K + ((size_t)b * LKK + k0 + k4) * DH + d0 + d4;
#pragma unroll
    for (int j = 0; j < 4; ++j) rk[j] = *(const f32x4*)(Kp + (size_t)j * DH);
    unsigned short* Kbp = Kb + ((size_t)b * LKK + k0 + k4) * DH + d0 + d4;
#pragma unroll
    for (int j = 0; j < 4; ++j) {
        u32x2 w;
        w[0] = pack_bf16x2(rk[j][0], rk[j][1]);
        w[1] = pack_bf16x2(rk[j][2], rk[j][3]);
        *(u32x2*)(Kbp + (size_t)j * DH) = w;
    }
#pragma unroll
    for (int c = 0; c < 4; ++c) {
        u32x2 w;
        w[0] = pack_bf16x2(rk[0][c], rk[1][c]);
        w[1] = pack_bf16x2(rk[2][c], rk[3][c]);
        *(u32x2*)&T[(d4 + c) * 68 + k4] = w;
    }
    __syncthreads();
    const int d  = t >> 2;
    const int kc = (t & 3) * 16;
    u32x2 a0 = *(const u32x2*)&T[d * 68 + kc];
    u32x2 a1 = *(const u32x2*)&T[d * 68 + kc + 4];
    u32x2 a2 = *(const u32x2*)&T[d * 68 + kc + 8];
    u32x2 a3 = *(const u32x2*)&T[d * 68 + kc + 12];
    unsigned short* dst = KT + ((size_t)b * DH + d0 + d) * LKK + k0 + kc;
    u32x4 w0; w0[0] = a0[0]; w0[1] = a0[1]; w0[2] = a1[0]; w0[3] = a1[1];
    u32x4 w1; w1[0] = a2[0]; w1[1] = a2[1]; w1[2] = a3[0]; w1[3] = a3[1];
    *(u32x4*)dst       = w0;
    *(u32x4*)(dst + 8) = w1;
}

// ================= 256x256 BK=64 pipelined mainloop (R5/R6 schedule) ===============
// Identical to R6 except template<bool WA>: on WA tiles (T>>3 == nxq), after the
// MFMA of each khalf phase (q=1,3), each wave reads back its OWN staged A-chunks
// (linear LDS addr = gload_lds dest), unpacks bf16->f32, scales by iv, stores to
// attn. Hazard audit: region (par,kh) is overwritten by a stage issued >=1
// end-barrier after this phase; read-back is intra-wave ordered + lgkm-drained.
// Stores enter vmcnt -> counted vmcnt(8) drains oldest (loads) first: stricter,
// safe (R7's lesson: vmcnt accounting is instruction-count per wave).
template<int LDA, int LDB, int NT, bool WA>
__device__ __forceinline__ void gemm8_mainloop(
    const unsigned short* __restrict__ Ab,
    const unsigned short* __restrict__ Bb,
    unsigned short* lA, unsigned short* lB,
    f32x4 (&acc)[8][4],
    float* attnR0, float* attnR1, float iv0, float iv1, int nxq)
{
    const int tid  = threadIdx.x;
    const int lane = tid & 63;
    const int wid  = tid >> 6;
    const int wm   = (wid & 1) * 128;
    const int wn   = (wid >> 1) * 64;
    const int lrow = lane & 15;
    const int quad = lane >> 4;
    const int slotsw = (quad ^ ((lrow >> 1) & 3)) * 8;

    const int srow0 = wid * 32 + (lane >> 2);
    const int srow1 = srow0 + 16;
    const int sc    = ((lane & 3) ^ ((lane >> 3) & 3)) * 8;

    auto stage = [&](int I) {
        if (I >= 4 * NT) return;
        const int tile = I >> 2;
        const int h    = I & 3;
        const int kh   = h >> 1;
        const int kb   = tile * 64 + kh * 32 + sc;
        const unsigned short* s = (h & 1) ? Bb : Ab;
        const int ld            = (h & 1) ? LDB : LDA;
        unsigned short* d = ((h & 1) ? lB : lA)
                          + (tile & 1) * 16384 + kh * 8192 + wid * 1024;
        __builtin_amdgcn_global_load_lds(GAS(s + (size_t)srow0 * ld + kb), LAS(d),       16, 0, 0);
        __builtin_amdgcn_global_load_lds(GAS(s + (size_t)srow1 * ld + kb), LAS(d + 512), 16, 0, 0);
    };

#pragma unroll
    for (int i = 0; i < 8; ++i)
#pragma unroll
        for (int j = 0; j < 4; ++j) acc[i][j] = (f32x4){0.f, 0.f, 0.f, 0.f};

#pragma unroll
    for (int I = 0; I < 6; ++I) stage(I);
    asm volatile("s_waitcnt vmcnt(8)" ::: "memory");
    __builtin_amdgcn_s_barrier();

    auto tilebody = [&](int T, int par) {
        bf16x8 bfr[4];
#pragma unroll
        for (int q = 0; q < 4; ++q) {
            const int kh = (q >> 1) * 8192;
            const int mh = (q & 1) * 4;
            if ((q & 1) == 0) {
#pragma unroll
                for (int nf = 0; nf < 4; ++nf)
                    bfr[nf] = dsr_b128(lds_addr(&lB[par + kh + (wn + nf * 16 + lrow) * 32 + slotsw]));
            }
            bf16x8 af[4];
#pragma unroll
            for (int mf = 0; mf < 4; ++mf)
                af[mf] = dsr_b128(lds_addr(&lA[par + kh + (wm + (mh + mf) * 16 + lrow) * 32 + slotsw]));

            if (q == 0)      stage(4 * T + 6);
            else if (q == 1) stage(4 * T + 7);
            else if (q == 2) { stage(4 * T + 8); stage(4 * T + 9); }

            __builtin_amdgcn_s_barrier();
            asm volatile("s_waitcnt lgkmcnt(0)" ::: "memory");
            __builtin_amdgcn_sched_barrier(0);
            __builtin_amdgcn_s_setprio(1);
#pragma unroll
            for (int mf = 0; mf < 4; ++mf)
#pragma unroll
                for (int nf = 0; nf < 4; ++nf)
                    acc[mh + mf][nf] = __builtin_amdgcn_mfma_f32_16x16x32_bf16(
                        af[mf], bfr[nf], acc[mh + mf][nf], 0, 0, 0);
            __builtin_amdgcn_s_setprio(0);

            if (WA && (q & 1) && (T >> 3) == nxq) {
                // read back this wave's own staged A-chunks of region (par, kh)
                unsigned short* Rg = lA + par + kh + wid * 1024;
                bf16x8 v0 = dsr_b128(lds_addr(Rg + (lane << 3)));
                bf16x8 v1 = dsr_b128(lds_addr(Rg + 512 + (lane << 3)));
                asm volatile("s_waitcnt lgkmcnt(0)" ::: "memory");
                __builtin_amdgcn_sched_barrier(0);
                const u32x4 u0 = __builtin_bit_cast(u32x4, v0);
                const u32x4 u1 = __builtin_bit_cast(u32x4, v1);
                const int kb = T * 64 + (q >> 1) * 32 + sc;
                f32x4 oA, oB, oC, oD;
#pragma unroll
                for (int j = 0; j < 2; ++j) {
                    oA[2*j]   = __builtin_bit_cast(float, u0[j] << 16) * iv0;
                    oA[2*j+1] = __builtin_bit_cast(float, u0[j] & 0xFFFF0000u) * iv0;
                    oB[2*j]   = __builtin_bit_cast(float, u0[j+2] << 16) * iv0;
                    oB[2*j+1] = __builtin_bit_cast(float, u0[j+2] & 0xFFFF0000u) * iv0;
                    oC[2*j]   = __builtin_bit_cast(float, u1[j] << 16) * iv1;
                    oC[2*j+1] = __builtin_bit_cast(float, u1[j] & 0xFFFF0000u) * iv1;
                    oD[2*j]   = __builtin_bit_cast(float, u1[j+2] << 16) * iv1;
                    oD[2*j+1] = __builtin_bit_cast(float, u1[j+2] & 0xFFFF0000u) * iv1;
                }
                *(f32x4*)(attnR0 + kb)     = oA;
                *(f32x4*)(attnR0 + kb + 4) = oB;
                *(f32x4*)(attnR1 + kb)     = oC;
                *(f32x4*)(attnR1 + kb + 4) = oD;
            }

            if (q == 1) {
                if (T < NT - 1)       asm volatile("s_waitcnt vmcnt(8)" ::: "memory");
                else                  asm volatile("s_waitcnt vmcnt(0)" ::: "memory");
            } else if (q == 3) {
                if (T < NT - 2)       asm volatile("s_waitcnt vmcnt(8)" ::: "memory");
                else if (T == NT - 2) asm volatile("s_waitcnt vmcnt(4)" ::: "memory");
            }
            __builtin_amdgcn_s_barrier();
        }
    };

    for (int T = 0; T < NT; T += 2) {
        tilebody(T,     0);
        tilebody(T + 1, 16384);
    }
}

// ---------------- GEMM1: FUSED -> ab = bf16(e), rowsum atomics; else S f32 ---------
template<bool FUSED>
__global__ __launch_bounds__(512, 2)
void qk8(const unsigned short* __restrict__ Qb, const unsigned short* __restrict__ Kb,
         const float* __restrict__ M, float* __restrict__ S,
         unsigned short* __restrict__ ab, float* __restrict__ Rs) {
    __shared__ __align__(16) unsigned short lA[32768];
    __shared__ __align__(16) unsigned short lB[32768];

    const int l   = blockIdx.x;
    const int swz = (l & 7) * 64 + (l >> 3);
    const int b   = swz >> 6;
    const int my  = (swz >> 3) & 7;
    const int nx  = swz & 7;
    const int q0  = my * 256;
    const int n0  = nx * 256;

    const unsigned short* Ap = Qb + ((size_t)b * LQ  + q0) * DH;
    const unsigned short* Bp = Kb + ((size_t)b * LKK + n0) * DH;

    f32x4 acc[8][4];
    gemm8_mainloop<DH, DH, DH / 64, false>(Ap, Bp, lA, lB, acc,
                                           nullptr, nullptr, 0.f, 0.f, 0);

    const int lane = threadIdx.x & 63;
    const int wid  = threadIdx.x >> 6;
    const int wm   = (wid & 1) * 128;
    const int wn   = (wid >> 1) * 64;
    const int lrow = lane & 15;
    const int quad = lane >> 4;

    // C/D layout: col = lane&15, row = quad*4 + r (m89/m91)
    const size_t base = (size_t)b * LQ * LKK;
    float rp[8][4];
#pragma unroll
    for (int mf = 0; mf < 8; ++mf) {
#pragma unroll
        for (int r = 0; r < 4; ++r) {
            const int row = q0 + wm + mf * 16 + quad * 4 + r;
            const size_t rb = base + (size_t)row * LKK;
            float rs = 0.f;
#pragma unroll
            for (int nf = 0; nf < 4; ++nf) {
                const int col = n0 + wn + nf * 16 + lrow;
                if (FUSED) {
                    // e = exp(S'); |S'| <= ~6 so exp is f32-safe without max-sub.
                    const float e = __expf(acc[mf][nf][r] * SCALE * M[rb + col]);
                    ab[rb + col] = pack_bf16(e);
                    rs += e;
                } else {
                    S[rb + col] = acc[mf][nf][r] * SCALE * M[rb + col];
                }
            }
            rp[mf][r] = rs;
        }
    }

    if (FUSED) {
        // reduce each row-partial across the 16 lanes (lrow) sharing it
#pragma unroll
        for (int mf = 0; mf < 8; ++mf)
#pragma unroll
            for (int r = 0; r < 4; ++r) {
                float v = rp[mf][r];
                v += __shfl_xor(v, 1, 64);
                v += __shfl_xor(v, 2, 64);
                v += __shfl_xor(v, 4, 64);
                v += __shfl_xor(v, 8, 64);
                rp[mf][r] = v;
            }
        if (lrow == 0) {
            float* Rb = Rs + (size_t)b * LQ + q0 + wm + quad * 4;
#pragma unroll
            for (int mf = 0; mf < 8; ++mf)
#pragma unroll
                for (int r = 0; r < 4; ++r)
                    atomicAdd(&Rb[mf * 16 + r], rp[mf][r]);
        }
    }
}

// ---------------- legacy softmax (fallback path): normalize f32 in place ----------
__global__ __launch_bounds__(256)
void softmax_kernel(float* __restrict__ A) {
    const int row  = blockIdx.x * 4 + (threadIdx.x >> 6);
    const int lane = threadIdx.x & 63;
    float* p = A + (size_t)row * LKK;

    f32x4 v[8];
#pragma unroll
    for (int i = 0; i < 8; ++i) v[i] = *(const f32x4*)(p + i * 256 + lane * 4);

    float m = v[0][0];
#pragma unroll
    for (int i = 0; i < 8; ++i)
#pragma unroll
        for (int j = 0; j < 4; ++j) m = fmaxf(m, v[i][j]);
#pragma unroll
    for (int o = 32; o >= 1; o >>= 1) m = fmaxf(m, __shfl_xor(m, o, 64));

    float s = 0.f;
#pragma unroll
    for (int i = 0; i < 8; ++i)
#pragma unroll
        for (int j = 0; j < 4; ++j) { v[i][j] = __expf(v[i][j] - m); s += v[i][j]; }
#pragma unroll
    for (int o = 32; o >= 1; o >>= 1) s += __shfl_xor(s, o, 64);
    const float inv = 1.f / s;

#pragma unroll
    for (int i = 0; i < 8; ++i) {
#pragma unroll
        for (int j = 0; j < 4; ++j) v[i][j] *= inv;
        *(f32x4*)(p + i * 256 + lane * 4) = v[i];
    }
}

// ---------------- GEMM2: ctx = (e_bf * KT_bf) * inv; writes attn in-loop ----------
__global__ __launch_bounds__(512, 2)
void pk8(const unsigned short* __restrict__ Pb, const unsigned short* __restrict__ KT,
         const float* __restrict__ Rs, float* __restrict__ attn,
         float* __restrict__ C) {
    __shared__ __align__(16) unsigned short lA[32768];
    __shared__ __align__(16) unsigned short lB[32768];

    const int l   = blockIdx.x;
    const int swz = (l & 7) * 32 + (l >> 3);
    const int b   = swz >> 5;
    const int my  = (swz >> 2) & 7;
    const int nx  = swz & 3;
    const int q0  = my * 256;
    const int n0  = nx * 256;   // d offset

    const unsigned short* Ap = Pb + ((size_t)b * LQ + q0) * LKK;
    const unsigned short* Bp = KT + ((size_t)b * DH + n0) * LKK;

    const int lane = threadIdx.x & 63;
    const int wid  = threadIdx.x >> 6;
    const int srow0 = wid * 32 + (lane >> 2);
    const float iv0 = 1.f / Rs[(size_t)b * LQ + q0 + srow0];
    const float iv1 = 1.f / Rs[(size_t)b * LQ + q0 + srow0 + 16];
    float* aR0 = attn + ((size_t)b * LQ + q0 + srow0) * LKK;
    float* aR1 = aR0 + (size_t)16 * LKK;

    f32x4 acc[8][4];
    gemm8_mainloop<LKK, LKK, LKK / 64, true>(Ap, Bp, lA, lB, acc,
                                             aR0, aR1, iv0, iv1, nx);

    const int wm   = (wid & 1) * 128;
    const int wn   = (wid >> 1) * 64;
    const int lrow = lane & 15;
    const int quad = lane >> 4;

    const float* Rsb = Rs + (size_t)b * LQ + q0;
    const size_t cb = (size_t)b * LQ * DH;
#pragma unroll
    for (int mf = 0; mf < 8; ++mf) {
#pragma unroll
        for (int r = 0; r < 4; ++r) {
            const int row = wm + mf * 16 + quad * 4 + r;
            const float iv = 1.f / Rsb[row];
            const size_t rbase = cb + (size_t)(q0 + row) * DH;
#pragma unroll
            for (int nf = 0; nf < 4; ++nf)
                C[rbase + n0 + wn + nf * 16 + lrow] = acc[mf][nf][r] * iv;
        }
    }
}

// ---------------- GEMM2 fallback (128^2 2-phase): inline fp32->bf16 ----------------
constexpr int BM = 128, BN = 128, TK = 32;
constexpr int LDSS = 40;
__global__ __launch_bounds__(256, 2)
void pk_kernel(const float* __restrict__ P, const float* __restrict__ K,
               float* __restrict__ C) {
    __shared__ unsigned short lA[BM * LDSS];
    __shared__ unsigned short lB[BN * LDSS];

    const int b  = blockIdx.z;
    const int q0 = blockIdx.y * BM;
    const int n0 = blockIdx.x * BN;
    const float* Pp = P + (size_t)b * LQ * LKK + (size_t)q0 * LKK;
    const float* Kb = K + (size_t)b * LKK * DH;

    const int tid  = threadIdx.x;
    const int lane = tid & 63;
    const int wid  = tid >> 6;
    const int wm   = (wid & 1) * 64;
    const int wn   = (wid >> 1) * 64;
    const int lrow = lane & 15;
    const int quad = lane >> 4;

    f32x4 acc[4][4];
#pragma unroll
    for (int i = 0; i < 4; ++i)
#pragma unroll
        for (int j = 0; j < 4; ++j) acc[i][j] = (f32x4){0.f, 0.f, 0.f, 0.f};

    const int srow = tid >> 3;
    const int skq  = (tid & 7) << 2;
    const int tdb  = tid >> 3;
    const int tkb  = tid & 7;

    for (int k0 = 0; k0 < LKK; k0 += TK) {
        __syncthreads();
#pragma unroll
        for (int i = 0; i < 4; ++i) {
            const int row = i * 32 + srow;
            const f32x4 va = *(const f32x4*)(Pp + (size_t)row * LKK + k0 + skq);
            unsigned* pa = (unsigned*)&lA[row * LDSS + skq];
            pa[0] = pack_bf16x2(va[0], va[1]);
            pa[1] = pack_bf16x2(va[2], va[3]);
        }
        f32x4 rk[4];
#pragma unroll
        for (int j = 0; j < 4; ++j)
            rk[j] = *(const f32x4*)(Kb + (size_t)(k0 + tkb * 4 + j) * DH + n0 + tdb * 4);
#pragma unroll
        for (int c = 0; c < 4; ++c) {
            unsigned* pb = (unsigned*)&lB[(tdb * 4 + c) * LDSS + tkb * 4];
            pb[0] = pack_bf16x2(rk[0][c], rk[1][c]);
            pb[1] = pack_bf16x2(rk[2][c], rk[3][c]);
        }
        __syncthreads();

        bf16x8 af[4], bfr[4];
#pragma unroll
        for (int i = 0; i < 4; ++i) {
            af[i]  = *(const bf16x8*)&lA[(wm + i * 16 + lrow) * LDSS + quad * 8];
            bfr[i] = *(const bf16x8*)&lB[(wn + i * 16 + lrow) * LDSS + quad * 8];
        }
#pragma unroll
        for (int i = 0; i < 4; ++i)
#pragma unroll
            for (int j = 0; j < 4; ++j)
                acc[i][j] = __builtin_amdgcn_mfma_f32_16x16x32_bf16(af[i], bfr[j], acc[i][j], 0, 0, 0);
    }

    const size_t cb = (size_t)b * LQ * DH;
#pragma unroll
    for (int i = 0; i < 4; ++i) {
#pragma unroll
        for (int r = 0; r < 4; ++r) {
            const int row = q0 + wm + i * 16 + quad * 4 + r;
            const size_t rbase = cb + (size_t)row * DH;
#pragma unroll
            for (int j = 0; j < 4; ++j)
                C[rbase + n0 + wn + j * 16 + lrow] = acc[i][j][r];
        }
    }
}

extern "C" void kernel_launch(void* const* d_in, const int* in_sizes, int n_in,
                              void* d_out, int out_size, void* d_ws, size_t ws_size,
                              hipStream_t stream) {
    const float* Q = (const float*)d_in[0];
    const float* K = (const float*)d_in[1];
    const float* M = (const float*)d_in[2];

    constexpr size_t QEL  = (size_t)BATCH * LQ * DH;    // 16,777,216 (ctx elems)
    constexpr size_t AEL  = (size_t)BATCH * LQ * LKK;   // 33,554,432 (attn elems)
    constexpr size_t KTEL = (size_t)BATCH * DH * LKK;   // 16,777,216
    constexpr size_t REL  = (size_t)BATCH * LQ;         // 16,384 row sums

    float* ctx  = (float*)d_out;
    float* attn = ctx + QEL;

    // bf16 Q/K scratch inside the (not-yet-written) ctx region: 2*QEL*2B == QEL*4B.
    unsigned short* Qb = (unsigned short*)ctx;
    unsigned short* Kb = Qb + QEL;

    const bool wsOK = ws_size >= (KTEL + AEL) * sizeof(unsigned short)
                               + REL * sizeof(float);
    unsigned short* KT = (unsigned short*)d_ws;
    unsigned short* ab = KT + KTEL;
    float* Rs = (float*)(ab + AEL);

    if (wsOK) {
        cvt_kernel<<<dim3(4096), 256, 0, stream>>>(Q, K, Qb, Kb, Rs);   // Q + zero Rs
        kt_kernel<<<dim3(DH / 64, LKK / 64, BATCH), 256, 0, stream>>>(K, KT, Kb);
        qk8<true><<<dim3(BATCH * (LQ / 256) * (LKK / 256)), 512, 0, stream>>>(
            Qb, Kb, M, nullptr, ab, Rs);
        pk8<<<dim3(BATCH * (LQ / 256) * (DH / 256)), 512, 0, stream>>>(
            ab, KT, Rs, attn, ctx);
    } else {
        cvt_kernel<<<dim3(8192), 256, 0, stream>>>(Q, K, Qb, Kb, nullptr);
        qk8<false><<<dim3(BATCH * (LQ / 256) * (LKK / 256)), 512, 0, stream>>>(
            Qb, Kb, M, attn, nullptr, nullptr);
        softmax_kernel<<<dim3(BATCH * LQ / 4), 256, 0, stream>>>(attn);
        pk_kernel<<<dim3(DH / BN, LQ / BM, BATCH), 256, 0, stream>>>(attn, K, ctx);
    }
}